// Round 3
// baseline (892.936 us; speedup 1.0000x reference)
//
#include <hip/hip_runtime.h>
#include <hip/hip_bf16.h>

// Problem constants (B,N,C,NF) = (4,512,128,96)
#define NB 4
#define NN 512
#define CC 128

typedef __bf16 bf16x8 __attribute__((ext_vector_type(8)));
typedef __bf16 bf16x4 __attribute__((ext_vector_type(4)));
typedef float  f32x4  __attribute__((ext_vector_type(4)));

// LDS-only barrier: drains lgkmcnt but leaves global loads (weight prefetch)
// in flight across the barrier — avoids the vmcnt(0) drain __syncthreads emits.
__device__ __forceinline__ void barrier_lds() {
    __builtin_amdgcn_s_waitcnt(0xC07F);  // lgkmcnt(0), vmcnt/expcnt unrestricted
    __builtin_amdgcn_fence(__ATOMIC_RELEASE, "workgroup", "local");
    __builtin_amdgcn_s_barrier();
    __builtin_amdgcn_fence(__ATOMIC_ACQUIRE, "workgroup", "local");
}

__device__ __forceinline__ float lrelu(float v) { return fmaxf(v, 0.01f * v); }

// ---------- conversion prepass: x,w1,w4 -> bf16; w2,w3 -> fp8 e4m3 ----------
__global__ void cvt_all(const float* __restrict__ x,  __bf16* __restrict__ xb,
                        const float* __restrict__ w1, __bf16* __restrict__ w1b,
                        const float* __restrict__ w4, __bf16* __restrict__ w4b,
                        const float* __restrict__ w2, int* __restrict__ w2f,
                        const float* __restrict__ w3, int* __restrict__ w3f)
{
    int idx = blockIdx.x * blockDim.x + threadIdx.x;
    if (idx < 73984) {
        const float* s; __bf16* d; int off;
        if      (idx < 65536) { s = x;  d = xb;  off = idx; }            // 262144 f32
        else if (idx < 71680) { s = w1; d = w1b; off = idx - 65536; }    //  24576
        else                  { s = w4; d = w4b; off = idx - 71680; }    //   9216
        float4 v = ((const float4*)s)[off];
        bf16x4 o = { (__bf16)v.x, (__bf16)v.y, (__bf16)v.z, (__bf16)v.w };
        ((bf16x4*)d)[off] = o;
    } else if (idx < 87808) {
        const float* s; int* d; int off;
        if (idx < 83200) { s = w2; d = w2f; off = idx - 73984; }         //  36864
        else             { s = w3; d = w3f; off = idx - 83200; }         //  18432
        float4 v = ((const float4*)s)[off];
        int p = __builtin_amdgcn_cvt_pk_fp8_f32(v.x, v.y, 0, false);
        p     = __builtin_amdgcn_cvt_pk_fp8_f32(v.z, v.w, p, true);
        d[off] = p;
    }
}

// ---------------- fused edge-MLP kernel -------------------------------------
// block: 64 edges = 4 i x 16 j, 4 waves. Orientation h^T = W * act^T:
// A = weights (regs, prefetched a layer ahead), B = acts (LDS), D rows = 4
// consecutive out-channels per lane.
// LDS: AbufB = d bf16 (272B rows) / h2 fp8 (200B rows)
//      BbufB = h1 fp8 (200B rows) / h3 bf16 (208B rows)   => 31.2 KB, 5 blk/CU
__global__ __launch_bounds__(256, 5) void mlp_edges(
    const __bf16* __restrict__ xb,
    const __bf16* __restrict__ w1b, const float* __restrict__ b1,
    const unsigned char* __restrict__ w2f, const float* __restrict__ b2,
    const unsigned char* __restrict__ w3f, const float* __restrict__ b3,
    const __bf16* __restrict__ w4b, const float* __restrict__ b4,
    const float* __restrict__ w5,  const float* __restrict__ b5,
    float* __restrict__ out)
{
    __shared__ __align__(16) unsigned char AbufB[64 * 272];
    __shared__ __align__(16) unsigned char BbufB[64 * 208];
    __shared__ float red[128];

    const int t = threadIdx.x;
    const int lane = t & 63, wave = t >> 6;
    const int l15 = lane & 15, q = lane >> 4, q8 = q * 8;
    const int j0 = blockIdx.x * 16, i0 = blockIdx.y * 4, b = blockIdx.z;

    // ---- prefetch w1 (bf16) + b1 ----
    bf16x8 w1f[3][4]; f32x4 b1v[3];
#pragma unroll
    for (int u = 0; u < 3; ++u) {
        const int ch = (wave + u * 4) * 16;
        b1v[u] = *(const f32x4*)(b1 + ch + q * 4);
#pragma unroll
        for (int k = 0; k < 4; ++k)
            w1f[u][k] = *(const bf16x8*)(w1b + (size_t)(ch + l15) * 128 + k * 32 + q8);
    }

    // ---- stage d = |x_i - x_j| (bf16, 272B rows) ----
    {
        const int m = t >> 2, c0 = (t & 3) * 32;
        const __bf16* xi = xb + ((size_t)b * NN + (i0 + (m >> 4))) * CC + c0;
        const __bf16* xj = xb + ((size_t)b * NN + (j0 + (m & 15))) * CC + c0;
        __bf16* drow = (__bf16*)(AbufB + m * 272) + c0;
#pragma unroll
        for (int c = 0; c < 32; c += 8) {
            bf16x8 a  = *(const bf16x8*)(xi + c);
            bf16x8 bb = *(const bf16x8*)(xj + c);
            bf16x8 dd;
#pragma unroll
            for (int uu = 0; uu < 8; ++uu) {
                float v = (float)a[uu] - (float)bb[uu];
                dd[uu] = (__bf16)fabsf(v);
            }
            *(bf16x8*)(drow + c) = dd;
        }
    }

    // ---- prefetch w2 (fp8) + b2 : stays in flight across the barrier ----
    long long w2v[3][6]; f32x4 b2v[3];
#pragma unroll
    for (int u = 0; u < 3; ++u) {
        const int ch = (wave + u * 4) * 16;
        b2v[u] = *(const f32x4*)(b2 + ch + q * 4);
#pragma unroll
        for (int k = 0; k < 6; ++k)
            w2v[u][k] = *(const long long*)(w2f + (size_t)(ch + l15) * 192 + k * 32 + q8);
    }

    barrier_lds();

    // ---- L1 (bf16 MFMA): d -> h1 (fp8, 200B rows) ----
#pragma unroll
    for (int nt = 0; nt < 4; ++nt) {
        f32x4 acc[3] = { b1v[0], b1v[1], b1v[2] };
        const __bf16* inrow = (const __bf16*)(AbufB + (nt * 16 + l15) * 272) + q8;
#pragma unroll
        for (int k = 0; k < 4; ++k) {
            bf16x8 bfrag = *(const bf16x8*)(inrow + k * 32);
#pragma unroll
            for (int u = 0; u < 3; ++u)
                acc[u] = __builtin_amdgcn_mfma_f32_16x16x32_bf16(w1f[u][k], bfrag, acc[u], 0, 0, 0);
        }
        unsigned char* orow = BbufB + (nt * 16 + l15) * 200 + q * 4;
#pragma unroll
        for (int u = 0; u < 3; ++u) {
            int p = __builtin_amdgcn_cvt_pk_fp8_f32(lrelu(acc[u][0]), lrelu(acc[u][1]), 0, false);
            p     = __builtin_amdgcn_cvt_pk_fp8_f32(lrelu(acc[u][2]), lrelu(acc[u][3]), p, true);
            *(int*)(orow + (wave + u * 4) * 16) = p;
        }
    }

    // ---- prefetch w3 (fp8, narrow split) + b3 ----
    long long w3v[3][6]; f32x4 b3v[3];
    const int mc0n = (wave & 1) * 3;      // narrow layers: ch chunks
    const int nlo  = (wave >> 1) * 2;     // narrow layers: edge tiles
#pragma unroll
    for (int u = 0; u < 3; ++u) {
        const int ch = (mc0n + u) * 16;
        b3v[u] = *(const f32x4*)(b3 + ch + q * 4);
#pragma unroll
        for (int k = 0; k < 6; ++k)
            w3v[u][k] = *(const long long*)(w3f + (size_t)(ch + l15) * 192 + k * 32 + q8);
    }

    barrier_lds();

    // ---- L2 (fp8 MFMA): h1 -> h2 (fp8, 200B rows) ----
#pragma unroll
    for (int nt = 0; nt < 4; ++nt) {
        f32x4 acc[3] = { b2v[0], b2v[1], b2v[2] };
        const unsigned char* inrow = BbufB + (nt * 16 + l15) * 200 + q8;
#pragma unroll
        for (int k = 0; k < 6; ++k) {
            long long bfrag = *(const long long*)(inrow + k * 32);
#pragma unroll
            for (int u = 0; u < 3; ++u)
                acc[u] = __builtin_amdgcn_mfma_f32_16x16x32_fp8_fp8(w2v[u][k], bfrag, acc[u], 0, 0, 0);
        }
        unsigned char* orow = AbufB + (nt * 16 + l15) * 200 + q * 4;
#pragma unroll
        for (int u = 0; u < 3; ++u) {
            int p = __builtin_amdgcn_cvt_pk_fp8_f32(lrelu(acc[u][0]), lrelu(acc[u][1]), 0, false);
            p     = __builtin_amdgcn_cvt_pk_fp8_f32(lrelu(acc[u][2]), lrelu(acc[u][3]), p, true);
            *(int*)(orow + (wave + u * 4) * 16) = p;
        }
    }

    // ---- prefetch w4 (bf16, narrow) + b4 + w5 ----
    bf16x8 w4f[3][3]; f32x4 b4v[3], w5v[3];
#pragma unroll
    for (int u = 0; u < 3; ++u) {
        const int ch = (mc0n + u) * 16;
        b4v[u] = *(const f32x4*)(b4 + ch + q * 4);
        w5v[u] = *(const f32x4*)(w5 + ch + q * 4);
#pragma unroll
        for (int k = 0; k < 3; ++k)
            w4f[u][k] = *(const bf16x8*)(w4b + (size_t)(ch + l15) * 96 + k * 32 + q8);
    }

    barrier_lds();

    // ---- L3 (fp8 MFMA): h2 -> h3 (bf16, 104-elem rows) ----
#pragma unroll
    for (int ntl = 0; ntl < 2; ++ntl) {
        const int nt = nlo + ntl;
        f32x4 acc[3] = { b3v[0], b3v[1], b3v[2] };
        const unsigned char* inrow = AbufB + (nt * 16 + l15) * 200 + q8;
#pragma unroll
        for (int k = 0; k < 6; ++k) {
            long long bfrag = *(const long long*)(inrow + k * 32);
#pragma unroll
            for (int u = 0; u < 3; ++u)
                acc[u] = __builtin_amdgcn_mfma_f32_16x16x32_fp8_fp8(w3v[u][k], bfrag, acc[u], 0, 0, 0);
        }
        __bf16* orow = (__bf16*)(BbufB) + (nt * 16 + l15) * 104 + q * 4;
#pragma unroll
        for (int u = 0; u < 3; ++u) {
            bf16x4 o;
#pragma unroll
            for (int r = 0; r < 4; ++r) o[r] = (__bf16)lrelu(acc[u][r]);
            *(bf16x4*)(orow + (mc0n + u) * 16) = o;
        }
    }

    barrier_lds();

    // ---- L4 (bf16 MFMA) + L5 dot in registers -> logit ----
#pragma unroll
    for (int ntl = 0; ntl < 2; ++ntl) {
        const int nt = nlo + ntl;
        f32x4 acc[3] = { b4v[0], b4v[1], b4v[2] };
        const __bf16* inrow = (const __bf16*)(BbufB) + (nt * 16 + l15) * 104 + q8;
#pragma unroll
        for (int k = 0; k < 3; ++k) {
            bf16x8 bfrag = *(const bf16x8*)(inrow + k * 32);
#pragma unroll
            for (int u = 0; u < 3; ++u)
                acc[u] = __builtin_amdgcn_mfma_f32_16x16x32_bf16(w4f[u][k], bfrag, acc[u], 0, 0, 0);
        }
        float p = 0.f;
#pragma unroll
        for (int u = 0; u < 3; ++u)
#pragma unroll
            for (int r = 0; r < 4; ++r)
                p += lrelu(acc[u][r]) * w5v[u][r];
        p += __shfl_xor(p, 16, 64);   // sum over 4 quads (k-parts of w5 dot)
        p += __shfl_xor(p, 32, 64);
        if (q == 0) red[(wave * 2 + ntl) * 16 + l15] = p;
    }

    barrier_lds();

    if ((wave & 1) == 0 && lane < 32) {
        const int ntl = lane >> 4, e = lane & 15;
        const float logit = red[(wave * 2 + ntl) * 16 + e]
                          + red[((wave + 1) * 2 + ntl) * 16 + e] + b5[0];
        const int i = i0 + (wave >> 1) * 2 + ntl;
        const int j = j0 + e;
        out[(((size_t)b * NN + i) * NN + j) * 2 + 1] = logit;
    }
}

// ---------------- softmax over j per (b,i) row, in place on out -------------
__global__ __launch_bounds__(256) void softmax_rows(float* __restrict__ out)
{
    const int row = blockIdx.x;           // b*512 + i
    const int i   = row & (NN - 1);
    float* base = out + (size_t)row * (NN * 2);
    const int t = threadIdx.x;

    float v0 = base[t * 2 + 1];
    float v1 = base[(t + 256) * 2 + 1];
    if (t == i)       v0 = -__builtin_inff();   // self-edge mask
    if (t + 256 == i) v1 = -__builtin_inff();

    float mx = fmaxf(v0, v1);
#pragma unroll
    for (int off = 32; off; off >>= 1) mx = fmaxf(mx, __shfl_xor(mx, off, 64));
    __shared__ float sm[4], ss[4];
    const int wave = t >> 6, lane = t & 63;
    if (lane == 0) sm[wave] = mx;
    __syncthreads();
    mx = fmaxf(fmaxf(sm[0], sm[1]), fmaxf(sm[2], sm[3]));

    const float e0 = __expf(v0 - mx), e1 = __expf(v1 - mx);
    float s = e0 + e1;
#pragma unroll
    for (int off = 32; off; off >>= 1) s += __shfl_xor(s, off, 64);
    if (lane == 0) ss[wave] = s;
    __syncthreads();
    s = ss[0] + ss[1] + ss[2] + ss[3];
    const float inv = 1.0f / s;

    float2* o2 = (float2*)base;
    o2[t]       = make_float2(t == i ? 1.f : 0.f,         e0 * inv);
    o2[t + 256] = make_float2((t + 256) == i ? 1.f : 0.f, e1 * inv);
}

// ---------------- host launch ----------------
extern "C" void kernel_launch(void* const* d_in, const int* in_sizes, int n_in,
                              void* d_out, int out_size, void* d_ws, size_t ws_size,
                              hipStream_t stream) {
    const float* x  = (const float*)d_in[0];
    // d_in[1] = W_id (pure eye broadcast; synthesized in-kernel)
    const float* w1 = (const float*)d_in[2];
    const float* b1 = (const float*)d_in[3];
    const float* w2 = (const float*)d_in[4];
    const float* b2 = (const float*)d_in[5];
    const float* w3 = (const float*)d_in[6];
    const float* b3 = (const float*)d_in[7];
    const float* w4 = (const float*)d_in[8];
    const float* b4 = (const float*)d_in[9];
    const float* w5 = (const float*)d_in[10];
    const float* b5 = (const float*)d_in[11];
    float* out = (float*)d_out;

    // ws: xb 524288 | w1b 49152 | w4b 18432 | w2f 36864 | w3f 18432
    char* ws = (char*)d_ws;
    __bf16* xb  = (__bf16*)(ws);
    __bf16* w1b = (__bf16*)(ws + 524288);
    __bf16* w4b = (__bf16*)(ws + 573440);
    unsigned char* w2f = (unsigned char*)(ws + 591872);
    unsigned char* w3f = (unsigned char*)(ws + 628736);

    cvt_all<<<(87808 + 255) / 256, 256, 0, stream>>>(x, xb, w1, w1b, w4, w4b,
                                                     w2, (int*)w2f, w3, (int*)w3f);

    dim3 grid(NN / 16, NN / 4, NB);   // j-tiles, i-tiles, batch
    mlp_edges<<<grid, 256, 0, stream>>>(xb, w1b, b1, w2f, b2, w3f, b3, w4b, b4,
                                        w5, b5, out);

    softmax_rows<<<NB * NN, 256, 0, stream>>>(out);
}

// Round 4
// 373.900 us; speedup vs baseline: 2.3882x; 2.3882x over previous
//
#include <hip/hip_runtime.h>
#include <hip/hip_bf16.h>

// Problem constants (B,N,C,NF) = (4,512,128,96)
#define NB 4
#define NN 512
#define CC 128

typedef __bf16 bf16x8 __attribute__((ext_vector_type(8)));
typedef __bf16 bf16x4 __attribute__((ext_vector_type(4)));
typedef float  f32x4  __attribute__((ext_vector_type(4)));

// LDS-only barrier: drains lgkmcnt but leaves global (weight) loads in flight.
__device__ __forceinline__ void barrier_lds() {
    __builtin_amdgcn_s_waitcnt(0xC07F);  // lgkmcnt(0), vmcnt/expcnt unrestricted
    __builtin_amdgcn_fence(__ATOMIC_RELEASE, "workgroup", "local");
    __builtin_amdgcn_s_barrier();
    __builtin_amdgcn_fence(__ATOMIC_ACQUIRE, "workgroup", "local");
}

__device__ __forceinline__ float lrelu(float v) { return fmaxf(v, 0.01f * v); }

__device__ __forceinline__ int pk4(float a, float b, float c, float d) {
    int p = __builtin_amdgcn_cvt_pk_fp8_f32(a, b, 0, false);
    return  __builtin_amdgcn_cvt_pk_fp8_f32(c, d, p, true);
}

// ---------- conversion prepass: x -> bf16; w1..w4 -> fp8 e4m3 ----------
__global__ void cvt_all(const float* __restrict__ x,  __bf16* __restrict__ xb,
                        const float* __restrict__ w1, int* __restrict__ w1f,
                        const float* __restrict__ w2, int* __restrict__ w2f,
                        const float* __restrict__ w3, int* __restrict__ w3f,
                        const float* __restrict__ w4, int* __restrict__ w4f)
{
    int idx = blockIdx.x * blockDim.x + threadIdx.x;
    if (idx < 65536) {                       // x: 262144 f32 -> bf16
        float4 v = ((const float4*)x)[idx];
        bf16x4 o = { (__bf16)v.x, (__bf16)v.y, (__bf16)v.z, (__bf16)v.w };
        ((bf16x4*)xb)[idx] = o;
    } else if (idx < 87808) {                // weights -> fp8 (4 f32 per int)
        const float* s; int* d; int off;
        if      (idx < 71680) { s = w1; d = w1f; off = idx - 65536; }  // 24576 f32
        else if (idx < 80896) { s = w2; d = w2f; off = idx - 71680; }  // 36864
        else if (idx < 85504) { s = w3; d = w3f; off = idx - 80896; }  // 18432
        else                  { s = w4; d = w4f; off = idx - 85504; }  //  9216
        float4 v = ((const float4*)s)[off];
        d[off] = pk4(v.x, v.y, v.z, v.w);
    }
}

// ---------------- fused edge-MLP kernel -------------------------------------
// block: 64 edges = 4 i x 16 j, 4 waves. Orientation h^T = W * act^T.
// All weights/activations fp8 e4m3; MFMA f32_16x16x32_fp8_fp8; JIT weight
// loads only (one layer live at a time — R3's prefetch-ahead spilled).
// LDS: Abuf rows 200B (d uses 144-stride region / h2 200), Bbuf rows 200B
//      (h1 200 / h3 104) => 25.6 KB + red => up to 6 blocks/CU.
__global__ __launch_bounds__(256, 5) void mlp_edges(
    const __bf16* __restrict__ xb,
    const unsigned char* __restrict__ w1p, const float* __restrict__ b1,
    const unsigned char* __restrict__ w2p, const float* __restrict__ b2,
    const unsigned char* __restrict__ w3p, const float* __restrict__ b3,
    const unsigned char* __restrict__ w4p, const float* __restrict__ b4,
    const float* __restrict__ w5,  const float* __restrict__ b5,
    float* __restrict__ out)
{
    __shared__ __align__(16) unsigned char AbufB[64 * 200];
    __shared__ __align__(16) unsigned char BbufB[64 * 200];
    __shared__ float red[128];

    const int t = threadIdx.x;
    const int lane = t & 63, wave = t >> 6;
    const int l15 = lane & 15, q = lane >> 4, q8 = q * 8;
    const int j0 = blockIdx.x * 16, i0 = blockIdx.y * 4, b = blockIdx.z;

    // ---- JIT w1 (fp8) + b1 : latency covered by d staging ----
    long long w1v[3][4]; f32x4 b1v[3];
#pragma unroll
    for (int u = 0; u < 3; ++u) {
        const int ch = (wave + u * 4) * 16;
        b1v[u] = *(const f32x4*)(b1 + ch + q * 4);
#pragma unroll
        for (int k = 0; k < 4; ++k)
            w1v[u][k] = *(const long long*)(w1p + (size_t)(ch + l15) * 128 + k * 32 + q8);
    }

    // ---- stage d = |x_i - x_j| as fp8, row stride 144 (16B aligned) ----
    {
        const int m = t >> 2, c0 = (t & 3) * 32;
        const __bf16* xi = xb + ((size_t)b * NN + (i0 + (m >> 4))) * CC + c0;
        const __bf16* xj = xb + ((size_t)b * NN + (j0 + (m & 15))) * CC + c0;
        unsigned char* drow = AbufB + m * 144 + c0;
#pragma unroll
        for (int h = 0; h < 2; ++h) {
            bf16x8 a0 = *(const bf16x8*)(xi + h * 16);
            bf16x8 a1 = *(const bf16x8*)(xi + h * 16 + 8);
            bf16x8 c0v = *(const bf16x8*)(xj + h * 16);
            bf16x8 c1v = *(const bf16x8*)(xj + h * 16 + 8);
            float dv[16];
#pragma unroll
            for (int u = 0; u < 8; ++u) {
                dv[u]     = fabsf((float)a0[u] - (float)c0v[u]);
                dv[u + 8] = fabsf((float)a1[u] - (float)c1v[u]);
            }
            int4 pk;
            pk.x = pk4(dv[0],  dv[1],  dv[2],  dv[3]);
            pk.y = pk4(dv[4],  dv[5],  dv[6],  dv[7]);
            pk.z = pk4(dv[8],  dv[9],  dv[10], dv[11]);
            pk.w = pk4(dv[12], dv[13], dv[14], dv[15]);
            *(int4*)(drow + h * 16) = pk;
        }
    }

    barrier_lds();

    // ---- L1 (fp8): d(144) -> h1(200), wide split ----
#pragma unroll
    for (int nt = 0; nt < 4; ++nt) {
        f32x4 acc[3] = { b1v[0], b1v[1], b1v[2] };
        const unsigned char* inrow = AbufB + (nt * 16 + l15) * 144 + q8;
#pragma unroll
        for (int k = 0; k < 4; ++k) {
            long long bfrag = *(const long long*)(inrow + k * 32);
#pragma unroll
            for (int u = 0; u < 3; ++u)
                acc[u] = __builtin_amdgcn_mfma_f32_16x16x32_fp8_fp8(w1v[u][k], bfrag, acc[u], 0, 0, 0);
        }
        unsigned char* orow = BbufB + (nt * 16 + l15) * 200 + q * 4;
#pragma unroll
        for (int u = 0; u < 3; ++u)
            *(int*)(orow + (wave + u * 4) * 16) =
                pk4(lrelu(acc[u][0]), lrelu(acc[u][1]), lrelu(acc[u][2]), lrelu(acc[u][3]));
    }

    // ---- JIT w2 + b2 (in flight across barrier) ----
    long long w2v[3][6]; f32x4 b2v[3];
#pragma unroll
    for (int u = 0; u < 3; ++u) {
        const int ch = (wave + u * 4) * 16;
        b2v[u] = *(const f32x4*)(b2 + ch + q * 4);
#pragma unroll
        for (int k = 0; k < 6; ++k)
            w2v[u][k] = *(const long long*)(w2p + (size_t)(ch + l15) * 192 + k * 32 + q8);
    }

    barrier_lds();

    // ---- L2 (fp8): h1(200) -> h2(200), wide split ----
#pragma unroll
    for (int nt = 0; nt < 4; ++nt) {
        f32x4 acc[3] = { b2v[0], b2v[1], b2v[2] };
        const unsigned char* inrow = BbufB + (nt * 16 + l15) * 200 + q8;
#pragma unroll
        for (int k = 0; k < 6; ++k) {
            long long bfrag = *(const long long*)(inrow + k * 32);
#pragma unroll
            for (int u = 0; u < 3; ++u)
                acc[u] = __builtin_amdgcn_mfma_f32_16x16x32_fp8_fp8(w2v[u][k], bfrag, acc[u], 0, 0, 0);
        }
        unsigned char* orow = AbufB + (nt * 16 + l15) * 200 + q * 4;
#pragma unroll
        for (int u = 0; u < 3; ++u)
            *(int*)(orow + (wave + u * 4) * 16) =
                pk4(lrelu(acc[u][0]), lrelu(acc[u][1]), lrelu(acc[u][2]), lrelu(acc[u][3]));
    }

    // ---- JIT w3 + b3 (narrow split) ----
    const int mc0n = (wave & 1) * 3;      // narrow layers: ch chunks
    const int nlo  = (wave >> 1) * 2;     // narrow layers: edge tiles
    long long w3v[3][6]; f32x4 b3v[3];
#pragma unroll
    for (int u = 0; u < 3; ++u) {
        const int ch = (mc0n + u) * 16;
        b3v[u] = *(const f32x4*)(b3 + ch + q * 4);
#pragma unroll
        for (int k = 0; k < 6; ++k)
            w3v[u][k] = *(const long long*)(w3p + (size_t)(ch + l15) * 192 + k * 32 + q8);
    }

    barrier_lds();

    // ---- L3 (fp8): h2(200) -> h3(104), narrow split ----
#pragma unroll
    for (int ntl = 0; ntl < 2; ++ntl) {
        const int nt = nlo + ntl;
        f32x4 acc[3] = { b3v[0], b3v[1], b3v[2] };
        const unsigned char* inrow = AbufB + (nt * 16 + l15) * 200 + q8;
#pragma unroll
        for (int k = 0; k < 6; ++k) {
            long long bfrag = *(const long long*)(inrow + k * 32);
#pragma unroll
            for (int u = 0; u < 3; ++u)
                acc[u] = __builtin_amdgcn_mfma_f32_16x16x32_fp8_fp8(w3v[u][k], bfrag, acc[u], 0, 0, 0);
        }
        unsigned char* orow = BbufB + (nt * 16 + l15) * 104 + q * 4;
#pragma unroll
        for (int u = 0; u < 3; ++u)
            *(int*)(orow + (mc0n + u) * 16) =
                pk4(lrelu(acc[u][0]), lrelu(acc[u][1]), lrelu(acc[u][2]), lrelu(acc[u][3]));
    }

    // ---- JIT w4 + b4 + w5 ----
    long long w4v[3][3]; f32x4 b4v[3], w5v[3];
#pragma unroll
    for (int u = 0; u < 3; ++u) {
        const int ch = (mc0n + u) * 16;
        b4v[u] = *(const f32x4*)(b4 + ch + q * 4);
        w5v[u] = *(const f32x4*)(w5 + ch + q * 4);
#pragma unroll
        for (int k = 0; k < 3; ++k)
            w4v[u][k] = *(const long long*)(w4p + (size_t)(ch + l15) * 96 + k * 32 + q8);
    }

    barrier_lds();

    // ---- L4 (fp8) + L5 dot in registers -> logit ----
#pragma unroll
    for (int ntl = 0; ntl < 2; ++ntl) {
        const int nt = nlo + ntl;
        f32x4 acc[3] = { b4v[0], b4v[1], b4v[2] };
        const unsigned char* inrow = BbufB + (nt * 16 + l15) * 104 + q8;
#pragma unroll
        for (int k = 0; k < 3; ++k) {
            long long bfrag = *(const long long*)(inrow + k * 32);
#pragma unroll
            for (int u = 0; u < 3; ++u)
                acc[u] = __builtin_amdgcn_mfma_f32_16x16x32_fp8_fp8(w4v[u][k], bfrag, acc[u], 0, 0, 0);
        }
        float p = 0.f;
#pragma unroll
        for (int u = 0; u < 3; ++u)
#pragma unroll
            for (int r = 0; r < 4; ++r)
                p += lrelu(acc[u][r]) * w5v[u][r];
        p += __shfl_xor(p, 16, 64);   // sum over 4 quads (k-parts of w5 dot)
        p += __shfl_xor(p, 32, 64);
        if (q == 0) red[(wave * 2 + ntl) * 16 + l15] = p;
    }

    barrier_lds();

    if ((wave & 1) == 0 && lane < 32) {
        const int ntl = lane >> 4, e = lane & 15;
        const float logit = red[(wave * 2 + ntl) * 16 + e]
                          + red[((wave + 1) * 2 + ntl) * 16 + e] + b5[0];
        const int i = i0 + (wave >> 1) * 2 + ntl;
        const int j = j0 + e;
        out[(((size_t)b * NN + i) * NN + j) * 2 + 1] = logit;
    }
}

// ---------------- softmax over j per (b,i) row, in place on out -------------
__global__ __launch_bounds__(256) void softmax_rows(float* __restrict__ out)
{
    const int row = blockIdx.x;           // b*512 + i
    const int i   = row & (NN - 1);
    float* base = out + (size_t)row * (NN * 2);
    const int t = threadIdx.x;

    float v0 = base[t * 2 + 1];
    float v1 = base[(t + 256) * 2 + 1];
    if (t == i)       v0 = -__builtin_inff();   // self-edge mask
    if (t + 256 == i) v1 = -__builtin_inff();

    float mx = fmaxf(v0, v1);
#pragma unroll
    for (int off = 32; off; off >>= 1) mx = fmaxf(mx, __shfl_xor(mx, off, 64));
    __shared__ float sm[4], ss[4];
    const int wave = t >> 6, lane = t & 63;
    if (lane == 0) sm[wave] = mx;
    __syncthreads();
    mx = fmaxf(fmaxf(sm[0], sm[1]), fmaxf(sm[2], sm[3]));

    const float e0 = __expf(v0 - mx), e1 = __expf(v1 - mx);
    float s = e0 + e1;
#pragma unroll
    for (int off = 32; off; off >>= 1) s += __shfl_xor(s, off, 64);
    if (lane == 0) ss[wave] = s;
    __syncthreads();
    s = ss[0] + ss[1] + ss[2] + ss[3];
    const float inv = 1.0f / s;

    float2* o2 = (float2*)base;
    o2[t]       = make_float2(t == i ? 1.f : 0.f,         e0 * inv);
    o2[t + 256] = make_float2((t + 256) == i ? 1.f : 0.f, e1 * inv);
}

// ---------------- host launch ----------------
extern "C" void kernel_launch(void* const* d_in, const int* in_sizes, int n_in,
                              void* d_out, int out_size, void* d_ws, size_t ws_size,
                              hipStream_t stream) {
    const float* x  = (const float*)d_in[0];
    // d_in[1] = W_id (pure eye broadcast; synthesized in-kernel)
    const float* w1 = (const float*)d_in[2];
    const float* b1 = (const float*)d_in[3];
    const float* w2 = (const float*)d_in[4];
    const float* b2 = (const float*)d_in[5];
    const float* w3 = (const float*)d_in[6];
    const float* b3 = (const float*)d_in[7];
    const float* w4 = (const float*)d_in[8];
    const float* b4 = (const float*)d_in[9];
    const float* w5 = (const float*)d_in[10];
    const float* b5 = (const float*)d_in[11];
    float* out = (float*)d_out;

    // ws: xb 524288 | w1f 24576 | w2f 36864 | w3f 18432 | w4f 9216
    char* ws = (char*)d_ws;
    __bf16*        xb  = (__bf16*)(ws);
    unsigned char* w1f = (unsigned char*)(ws + 524288);
    unsigned char* w2f = (unsigned char*)(ws + 548864);
    unsigned char* w3f = (unsigned char*)(ws + 585728);
    unsigned char* w4f = (unsigned char*)(ws + 604160);

    cvt_all<<<(87808 + 255) / 256, 256, 0, stream>>>(x, xb, w1, (int*)w1f,
                                                     w2, (int*)w2f, w3, (int*)w3f,
                                                     w4, (int*)w4f);

    dim3 grid(NN / 16, NN / 4, NB);   // j-tiles, i-tiles, batch
    mlp_edges<<<grid, 256, 0, stream>>>(xb, w1f, b1, w2f, b2, w3f, b3, w4f, b4,
                                        w5, b5, out);

    softmax_rows<<<NB * NN, 256, 0, stream>>>(out);
}